// Round 17
// baseline (261.441 us; speedup 1.0000x reference)
//
#include <hip/hip_runtime.h>
#include <hip/hip_bf16.h>

#define NN 20000
#define EE 320000
#define IN 128
#define HID 64
#define OUTC 128
#define NH 3
#define NEG 0.15f
#define IN2 320
#define HO1 192   // NH*HID
#define HO2 384   // NH*OUTC
#define NB_SCAN 79   // ceil(NN/256)
#define GRIDM128 157 // ceil(NN/128)
#define LDA 72       // 64 + 8 pad (bank-spread)

typedef __hip_bfloat16 bf16;
typedef __attribute__((ext_vector_type(8))) short short8;  // 8 bf16 = 4 VGPR
typedef __attribute__((ext_vector_type(4))) float f32x4;   // MFMA C/D frag

__device__ __forceinline__ float bf2f(bf16 v) { return __bfloat162float(v); }
__device__ __forceinline__ bf16 f2bf(float v) { return __float2bfloat16(v); }
__device__ __forceinline__ float lrelu(float s) { return fmaxf(s, NEG * s); }
__device__ __forceinline__ float lo16(unsigned int d) {
    union { unsigned int u; float f; } c; c.u = d << 16; return c.f;
}
__device__ __forceinline__ float hi16(unsigned int d) {
    union { unsigned int u; float f; } c; c.u = d & 0xffff0000u; return c.f;
}

// ---------------- CSR build (by dst) — proven rounds 4..16 ----------------
__global__ void k_count(const int* __restrict__ ei, int* __restrict__ cnt) {
    const int e = blockIdx.x * 256 + threadIdx.x;
    if (e < EE) atomicAdd(&cnt[ei[EE + e]], 1);
}

__global__ void k_scanA(const int* __restrict__ cnt, int* __restrict__ loc,
                        int* __restrict__ bsum) {
    __shared__ int sh[256];
    const int t = threadIdx.x;
    const int i = blockIdx.x * 256 + t;
    const int v = (i < NN) ? cnt[i] : 0;
    sh[t] = v; __syncthreads();
    for (int off = 1; off < 256; off <<= 1) {
        const int add = (t >= off) ? sh[t - off] : 0;
        __syncthreads();
        sh[t] += add; __syncthreads();
    }
    if (i < NN) loc[i] = sh[t];
    if (t == 255) bsum[blockIdx.x] = sh[255];
}

__global__ void k_scanB(int* __restrict__ bsum) {
    __shared__ int sh[128];
    const int t = threadIdx.x;
    const int v = (t < NB_SCAN) ? bsum[t] : 0;
    sh[t] = v; __syncthreads();
    for (int off = 1; off < 128; off <<= 1) {
        const int add = (t >= off) ? sh[t - off] : 0;
        __syncthreads();
        sh[t] += add; __syncthreads();
    }
    if (t < NB_SCAN) bsum[t] = sh[t] - v;
}

__global__ void k_scanC(const int* __restrict__ loc, const int* __restrict__ cnt,
                        const int* __restrict__ bsum, int* __restrict__ row_off,
                        int* __restrict__ fill) {
    const int i = blockIdx.x * 256 + threadIdx.x;
    if (i < NN) {
        const int ro = loc[i] - cnt[i] + bsum[blockIdx.x];
        row_off[i] = ro; fill[i] = ro;
    }
    if (i == 0) row_off[NN] = EE;
}

__global__ void k_scatter(const int* __restrict__ ei, int* __restrict__ fill,
                          int* __restrict__ csr_src) {
    const int e = blockIdx.x * 256 + threadIdx.x;
    if (e < EE) {
        const int p = atomicAdd(&fill[ei[EE + e]], 1);
        csr_src[p] = ei[e];
    }
}

// ---------------- merged pre-pass: xb cast + both weight transposes ------------
#define PREP_XB (NN * IN)                 // 2,560,000
#define PREP_W1 (2 * HO1 * IN)            // 49,152
#define PREP_W2 (2 * HO2 * IN2)           // 245,760
__global__ void k_prep(const float* __restrict__ x,
                       const float* __restrict__ Wl1, const float* __restrict__ Wr1,
                       const float* __restrict__ Wl2, const float* __restrict__ Wr2,
                       bf16* __restrict__ xb, bf16* __restrict__ Wt1,
                       bf16* __restrict__ Wt2) {
    int idx = blockIdx.x * 256 + threadIdx.x;
    if (idx < PREP_XB) { xb[idx] = f2bf(x[idx]); return; }
    idx -= PREP_XB;
    if (idx < PREP_W1) {
        const int n = idx / IN, k = idx - n * IN;
        const float* W = (n < HO1) ? Wl1 : Wr1;
        const int nn = (n < HO1) ? n : n - HO1;
        Wt1[idx] = f2bf(W[(size_t)k * HO1 + nn]);
        return;
    }
    idx -= PREP_W1;
    if (idx < PREP_W2) {
        const int n = idx / IN2, k = idx - n * IN2;
        const float* W = (n < HO2) ? Wl2 : Wr2;
        const int nn = (n < HO2) ? n : n - HO2;
        Wt2[idx] = f2bf(W[(size_t)k * HO2 + nn]);
    }
}

// ---------------- MFMA GEMM v3: 128x128 tile, LDS-staged, BK=64 (round 15/16) --
template <int K, int CH>
__launch_bounds__(256)
__global__ void gemm_mfma(const bf16* __restrict__ A0, int As0,   // k < 128
                          const bf16* __restrict__ A1, int As1,   // k >= 128
                          const bf16* __restrict__ Wt,
                          const float* __restrict__ bl, const float* __restrict__ br,
                          int NO, size_t planeN,
                          bf16* __restrict__ outl, bf16* __restrict__ outr) {
    __shared__ bf16 Asm[128 * LDA];
    __shared__ bf16 Bsm[128 * LDA];
    const int tid = threadIdx.x;
    const int w = tid >> 6, lane = tid & 63;
    const int quad = lane >> 4, l15 = lane & 15;
    const int r0 = (w >> 1) * 64;
    const int c0 = (w & 1) * 64;
    const int m0 = blockIdx.x * 128;
    const int n0 = blockIdx.y * 128;

    f32x4 acc[4][4];
#pragma unroll
    for (int nt = 0; nt < 4; ++nt) {
        const int col = n0 + c0 + nt * 16 + l15;
        const float b = (col < NO) ? bl[col] : br[col - NO];
#pragma unroll
        for (int mt = 0; mt < 4; ++mt) acc[mt][nt] = (f32x4){b, b, b, b};
    }

    int arow[4]; size_t boff[4]; int soff[4];
#pragma unroll
    for (int q = 0; q < 4; ++q) {
        const int s = q * 256 + tid;
        int r = m0 + (s >> 3); if (r >= NN) r = NN - 1;
        arow[q] = r;
        boff[q] = (size_t)(n0 + (s >> 3)) * K + (s & 7) * 8;
        soff[q] = (s >> 3) * LDA + (s & 7) * 8;
    }

    short8 pa[4], pb[4];
#pragma unroll
    for (int q = 0; q < 4; ++q) {
        const int s = q * 256 + tid;
        pa[q] = *(const short8*)(A0 + (size_t)arow[q] * As0 + (s & 7) * 8);
        pb[q] = *(const short8*)(Wt + boff[q]);
    }

#pragma unroll
    for (int ks = 0; ks < K; ks += 64) {
#pragma unroll
        for (int q = 0; q < 4; ++q) {
            *(short8*)&Asm[soff[q]] = pa[q];
            *(short8*)&Bsm[soff[q]] = pb[q];
        }
        __syncthreads();
        if (ks + 64 < K) {
            const int nks = ks + 64;
#pragma unroll
            for (int q = 0; q < 4; ++q) {
                const int s = q * 256 + tid;
                const bf16* ap = (K <= 128 || nks < 128)
                    ? (A0 + (size_t)arow[q] * As0 + nks + (s & 7) * 8)
                    : (A1 + (size_t)arow[q] * As1 + (nks - 128) + (s & 7) * 8);
                pa[q] = *(const short8*)ap;
                pb[q] = *(const short8*)(Wt + boff[q] + nks);
            }
        }
#pragma unroll
        for (int kq = 0; kq < 2; ++kq) {
            short8 af[4], bf[4];
#pragma unroll
            for (int mt = 0; mt < 4; ++mt)
                af[mt] = *(const short8*)&Asm[(r0 + mt * 16 + l15) * LDA + kq * 32 + quad * 8];
#pragma unroll
            for (int nt = 0; nt < 4; ++nt)
                bf[nt] = *(const short8*)&Bsm[(c0 + nt * 16 + l15) * LDA + kq * 32 + quad * 8];
#pragma unroll
            for (int mt = 0; mt < 4; ++mt)
#pragma unroll
                for (int nt = 0; nt < 4; ++nt)
                    acc[mt][nt] = __builtin_amdgcn_mfma_f32_16x16x32_bf16(af[mt], bf[nt], acc[mt][nt], 0, 0, 0);
        }
        __syncthreads();
    }

#pragma unroll
    for (int mt = 0; mt < 4; ++mt)
#pragma unroll
    for (int nt = 0; nt < 4; ++nt) {
        const int col = n0 + c0 + nt * 16 + l15;
        const int cc = (col < NO) ? col : col - NO;
        bf16* o = (col < NO) ? outl : outr;
        const int h = cc / CH, c = cc - h * CH;
#pragma unroll
        for (int r = 0; r < 4; ++r) {
            const int row = m0 + r0 + mt * 16 + quad * 4 + r;
            if (row < NN) o[h * planeN + (size_t)row * CH + c] = f2bf(acc[mt][nt][r]);
        }
    }
}

// xcd-pinned (dst, head) mapping: xcd = blk&7 (round-robin heuristic),
// head = xcd%3 -> h0:{0,3,6} h1:{1,4,7} h2:{2,5}; dst = slot*cnt + rank.
// Correctness is mapping-independent (each (dst,head) covered exactly once).
__device__ __forceinline__ bool pin_map(int blk, int& h, int& i) {
    const int xcd = blk & 7, slot = blk >> 3;
    h = xcd % 3;
    const int rank = xcd / 3;
    const int cnt = (h == 2) ? 2 : 3;
    i = slot * cnt + rank;
    return i < NN;
}
#define PIN_GRID 80000   // 8 xcd-groups x 10000 slots

// ---------------- gather1: 1 wave per (dst,head), xcd-pinned plane -------------
__global__ void gather1(const int* __restrict__ row_off, const int* __restrict__ csr_src,
                        const bf16* __restrict__ xl, const bf16* __restrict__ xr,
                        const float* __restrict__ att, const float* __restrict__ bias,
                        bf16* __restrict__ h1) {
    int h, i;
    if (!pin_map(blockIdx.x, h, i)) return;
    const int lane = threadIdx.x;        // 64
    const int g = lane >> 3;             // group 0..7 (edge slot)
    const int t = lane & 7;              // channels 8t..8t+7
    const unsigned short* xlu = (const unsigned short*)xl + (size_t)h * NN * HID;
    const unsigned short* xru = (const unsigned short*)xr + (size_t)h * NN * HID;
    float rv[8], av[8];
    {
        const uint4 ru = *(const uint4*)(xru + (size_t)i * HID + 8 * t);
        rv[0] = lo16(ru.x); rv[1] = hi16(ru.x);
        rv[2] = lo16(ru.y); rv[3] = hi16(ru.y);
        rv[4] = lo16(ru.z); rv[5] = hi16(ru.z);
        rv[6] = lo16(ru.w); rv[7] = hi16(ru.w);
#pragma unroll
        for (int c = 0; c < 8; ++c) av[c] = att[h * HID + 8 * t + c];
    }
    float acc[8] = {0.f, 0.f, 0.f, 0.f, 0.f, 0.f, 0.f, 0.f};
    float den = 0.f;
    const int kb = row_off[i], ke = row_off[i + 1];
    for (int p0 = kb; p0 < ke; p0 += 8) {
        const int idx = p0 + g;
        const int j = csr_src[idx < ke ? idx : ke - 1];
        const uint4 lu = *(const uint4*)(xlu + (size_t)j * HID + 8 * t);
        float lv[8];
        lv[0] = lo16(lu.x); lv[1] = hi16(lu.x);
        lv[2] = lo16(lu.y); lv[3] = hi16(lu.y);
        lv[4] = lo16(lu.z); lv[5] = hi16(lu.z);
        lv[6] = lo16(lu.w); lv[7] = hi16(lu.w);
        float p = 0.f;
#pragma unroll
        for (int c = 0; c < 8; ++c)
            p = fmaf(lrelu(lv[c] + rv[c]), av[c], p);
        p += __shfl_xor(p, 1, 64);
        p += __shfl_xor(p, 2, 64);
        p += __shfl_xor(p, 4, 64);
        const float ex = (idx < ke) ? __expf(p) : 0.f;   // |logit|<~8: fp32-safe
#pragma unroll
        for (int c = 0; c < 8; ++c) acc[c] = fmaf(ex, lv[c], acc[c]);
        den += ex;
    }
    __shared__ float part[8][HID];
    __shared__ float dsh[8];
    *(f32x4*)&part[g][8 * t]     = (f32x4){acc[0], acc[1], acc[2], acc[3]};
    *(f32x4*)&part[g][8 * t + 4] = (f32x4){acc[4], acc[5], acc[6], acc[7]};
    if (t == 0) dsh[g] = den;
    __syncthreads();
    const int c = lane;                  // 64 channels
    float num = 0.f, dd = 0.f;
#pragma unroll
    for (int q = 0; q < 8; ++q) { num += part[q][c]; dd += dsh[q]; }
    const float v = num / (dd + 1e-16f) + bias[h * HID + c];
    h1[(size_t)i * HO1 + h * HID + c] = f2bf(v > 0.f ? v : 0.f);
}

// ---------------- gather2: 1 wave per (dst,head), xcd-pinned plane -------------
// head0 -> fp32 into d_out; heads 1/2 -> bf16 planes. Combined by k_comb.
__global__ void gather2(const int* __restrict__ row_off, const int* __restrict__ csr_src,
                        const bf16* __restrict__ xl2, const bf16* __restrict__ xr2,
                        const float* __restrict__ att2,
                        float* __restrict__ out0, bf16* __restrict__ p1b,
                        bf16* __restrict__ p2b) {
    int h, i;
    if (!pin_map(blockIdx.x, h, i)) return;
    const int lane = threadIdx.x;        // 64
    const int g = lane >> 4;             // group 0..3 (edge slot)
    const int t = lane & 15;             // channels 8t..8t+7
    const unsigned short* xlu = (const unsigned short*)xl2 + (size_t)h * NN * OUTC;
    const unsigned short* xru = (const unsigned short*)xr2 + (size_t)h * NN * OUTC;
    float rv[8], av[8];
    {
        const uint4 ru = *(const uint4*)(xru + (size_t)i * OUTC + 8 * t);
        rv[0] = lo16(ru.x); rv[1] = hi16(ru.x);
        rv[2] = lo16(ru.y); rv[3] = hi16(ru.y);
        rv[4] = lo16(ru.z); rv[5] = hi16(ru.z);
        rv[6] = lo16(ru.w); rv[7] = hi16(ru.w);
#pragma unroll
        for (int c = 0; c < 8; ++c) av[c] = att2[h * OUTC + 8 * t + c];
    }
    float acc[8] = {0.f, 0.f, 0.f, 0.f, 0.f, 0.f, 0.f, 0.f};
    float den = 0.f;
    const int kb = row_off[i], ke = row_off[i + 1];
    for (int p0 = kb; p0 < ke; p0 += 4) {
        const int idx = p0 + g;
        const int j = csr_src[idx < ke ? idx : ke - 1];
        const uint4 lu = *(const uint4*)(xlu + (size_t)j * OUTC + 8 * t);
        float lv[8];
        lv[0] = lo16(lu.x); lv[1] = hi16(lu.x);
        lv[2] = lo16(lu.y); lv[3] = hi16(lu.y);
        lv[4] = lo16(lu.z); lv[5] = hi16(lu.z);
        lv[6] = lo16(lu.w); lv[7] = hi16(lu.w);
        float p = 0.f;
#pragma unroll
        for (int c = 0; c < 8; ++c)
            p = fmaf(lrelu(lv[c] + rv[c]), av[c], p);
        p += __shfl_xor(p, 1, 64);
        p += __shfl_xor(p, 2, 64);
        p += __shfl_xor(p, 4, 64);
        p += __shfl_xor(p, 8, 64);
        const float ex = (idx < ke) ? __expf(p) : 0.f;
#pragma unroll
        for (int c = 0; c < 8; ++c) acc[c] = fmaf(ex, lv[c], acc[c]);
        den += ex;
    }
    __shared__ float part[4][OUTC];
    __shared__ float dsh[4];
    *(f32x4*)&part[g][8 * t]     = (f32x4){acc[0], acc[1], acc[2], acc[3]};
    *(f32x4*)&part[g][8 * t + 4] = (f32x4){acc[4], acc[5], acc[6], acc[7]};
    if (t == 0) dsh[g] = den;
    __syncthreads();
    const float dd = dsh[0] + dsh[1] + dsh[2] + dsh[3];
    const float inv = 1.f / (dd + 1e-16f);
#pragma unroll
    for (int u = 0; u < 2; ++u) {
        const int c = lane + u * 64;
        const float val = (part[0][c] + part[1][c] + part[2][c] + part[3][c]) * inv;
        if (h == 0)      out0[(size_t)i * OUTC + c] = val;
        else if (h == 1) p1b[(size_t)i * OUTC + c] = f2bf(val);
        else             p2b[(size_t)i * OUTC + c] = f2bf(val);
    }
}

// out = relu((out + p1 + p2)/3 + bias)
__global__ void k_comb(float* __restrict__ out, const bf16* __restrict__ p1b,
                       const bf16* __restrict__ p2b, const float* __restrict__ bias2) {
    const int idx = blockIdx.x * 256 + threadIdx.x;
    if (idx >= NN * OUTC) return;
    const int c = idx & (OUTC - 1);
    const float v = (out[idx] + bf2f(p1b[idx]) + bf2f(p2b[idx])) * (1.f / 3.f) + bias2[c];
    out[idx] = v > 0.f ? v : 0.f;
}

extern "C" void kernel_launch(void* const* d_in, const int* in_sizes, int n_in,
                              void* d_out, int out_size, void* d_ws, size_t ws_size,
                              hipStream_t stream) {
    const float* x    = (const float*)d_in[0];
    const float* Wl1  = (const float*)d_in[1];
    const float* bl1  = (const float*)d_in[2];
    const float* Wr1  = (const float*)d_in[3];
    const float* br1  = (const float*)d_in[4];
    const float* att1 = (const float*)d_in[5];
    const float* bias1= (const float*)d_in[6];
    const float* Wl2  = (const float*)d_in[7];
    const float* bl2  = (const float*)d_in[8];
    const float* Wr2  = (const float*)d_in[9];
    const float* br2  = (const float*)d_in[10];
    const float* att2 = (const float*)d_in[11];
    const float* bias2= (const float*)d_in[12];
    const int*   ei   = (const int*)d_in[13];

    char* ws = (char*)d_ws;
    // Pool layout (bytes), peak 45,713,936 — byte-identical to proven rounds 10-16:
    //  [0,         5,120,000)  xb   bf16 [N,128]       -> p1b after gemm2 (5.12 MB)
    //  [5.12e6,   12,800,000)  h1b  bf16 [N,192]       -> p2b after gemm2 (5.12 MB used)
    //  [12.8e6,   20,480,000)  xl1 planar [3][N][64]   \ dead after gather1 ->
    //  [20.48e6,  28,160,000)  xr1 planar [3][N][64]   /  xl2 planar [3][N][128]
    //  [28.16e6,  43,520,000)  xr2 planar [3][N][128]
    //  [43.52e6,  45,124,104)  CSR: cnt/fill/loc/bsum/rowoff/csrsrc
    //  [45,124,112, 45,222,416)  Wt1 bf16 [384][128]
    //  [45,222,416, 45,713,936)  Wt2 bf16 [768][320]
    bf16*  xb     = (bf16*)(ws);
    bf16*  h1b    = (bf16*)(ws + 5120000);
    bf16*  xl1    = (bf16*)(ws + 12800000);
    bf16*  xr1    = (bf16*)(ws + 20480000);
    bf16*  xl2    = (bf16*)(ws + 12800000);   // alias: xl1/xr1 dead after gather1
    bf16*  xr2    = (bf16*)(ws + 28160000);
    bf16*  p1b    = (bf16*)(ws);              // alias: xb dead after gemm2
    bf16*  p2b    = (bf16*)(ws + 5120000);    // alias: h1b dead after gemm2
    int*   cnt    = (int*)(ws + 43520000);
    int*   fill   = (int*)(ws + 43600000);
    int*   loc    = (int*)(ws + 43680000);
    int*   bsum   = (int*)(ws + 43760000);
    int*   rowoff = (int*)(ws + 43764096);
    int*   csrsrc = (int*)(ws + 43844104);
    bf16*  Wt1    = (bf16*)(ws + 45124112);
    bf16*  Wt2    = (bf16*)(ws + 45222416);

    // ---- merged pre-pass ----
    k_prep<<<(PREP_XB + PREP_W1 + PREP_W2 + 255) / 256, 256, 0, stream>>>(
        x, Wl1, Wr1, Wl2, Wr2, xb, Wt1, Wt2);

    // ---- CSR build ----
    hipMemsetAsync(cnt, 0, NN * sizeof(int), stream);
    k_count<<<(EE + 255) / 256, 256, 0, stream>>>(ei, cnt);
    k_scanA<<<NB_SCAN, 256, 0, stream>>>(cnt, loc, bsum);
    k_scanB<<<1, 128, 0, stream>>>(bsum);
    k_scanC<<<NB_SCAN, 256, 0, stream>>>(loc, cnt, bsum, rowoff, fill);
    k_scatter<<<(EE + 255) / 256, 256, 0, stream>>>(ei, fill, csrsrc);

    // ---- layer 1 ----
    gemm_mfma<IN, HID><<<dim3(GRIDM128, HO2 / 128), 256, 0, stream>>>(
        xb, IN, (const bf16*)nullptr, 0, Wt1, bl1, br1, HO1,
        (size_t)NN * HID, xl1, xr1);
    gather1<<<PIN_GRID, 64, 0, stream>>>(rowoff, csrsrc, xl1, xr1, att1, bias1, h1b);

    // ---- layer 2 ----
    gemm_mfma<IN2, OUTC><<<dim3(GRIDM128, 2 * HO2 / 128), 256, 0, stream>>>(
        xb, IN, h1b, HO1, Wt2, bl2, br2, HO2,
        (size_t)NN * OUTC, xl2, xr2);
    gather2<<<PIN_GRID, 64, 0, stream>>>(rowoff, csrsrc, xl2, xr2, att2,
                                         (float*)d_out, p1b, p2b);
    k_comb<<<(NN * OUTC + 255) / 256, 256, 0, stream>>>((float*)d_out, p1b, p2b, bias2);
}